// Round 1
// 240.940 us; speedup vs baseline: 1.0058x; 1.0058x over previous
//
#include <hip/hip_runtime.h>
#include <math.h>

// SGC: K=2 hops of D^-1/2 (A+I) D^-1/2, then x@W+b, then log_softmax.
// N=100000, D=64, C=40, E=1600000.
//
// R9 (this round): attack latency/issue waste in the two gather kernels.
//  - perm[]: degree-grouped wave scheduling. build_csr counting-sorts each
//    512-row bucket by padded len; SpMM wave w takes rows perm[4w..4w+3]
//    (similar lens -> maxlen ~= len; ~55% of waves drop to 1 gather iter).
//    Output is per-row independent -> perm order cannot change results.
//  - v_pk_add_f32 accumulate: acc as float2 ext-vector, unpack = lshl+and,
//    then one packed add (3 VALU/dword vs 4).
//  - logits GEMV: replace 64x(ds_bpermute + 3x ds_read_b32) with one LDS
//    transpose of h (hl[16][68] pad) + transposed padded Wt[40][68];
//    inner loop = 4x ds_read_b128 + 12 FMA per 4 features.
//  - __launch_bounds__(256,6): let the 16-deep gather pipeline actually
//    hold 16 uint2 in flight (VGPR was capped at 32 -> ~4-deep realized).

#define D_FEAT 64
#define NCLS 40
#define BROWS 512       // rows per bucket
#define BROWS_LOG 9
#define BINCAP 10240    // per-bucket edge capacity (mean 8192, sd ~90)
#define CSRCAP 12288    // per-bucket csr capacity (max padded = 10240+3*512 = 11776)
#define EPT 25          // edges per thread in bin_edges (250 blocks)

typedef float v2f __attribute__((ext_vector_type(2)));

__device__ __forceinline__ unsigned pack_bf16_2(float lo, float hi) {
    unsigned ulo = __float_as_uint(lo);
    unsigned uhi = __float_as_uint(hi);
    ulo = (ulo + 0x7fffu + ((ulo >> 16) & 1u)) >> 16;           // RNE
    uhi = (uhi + 0x7fffu + ((uhi >> 16) & 1u)) & 0xffff0000u;   // RNE
    return uhi | ulo;
}

// packed-accumulate one dword (2 bf16 features) into a float2 accumulator
__device__ __forceinline__ void acc2p(unsigned u, v2f& a) {
    v2f v;
    v.x = __uint_as_float(u << 16);
    v.y = __uint_as_float(u & 0xffff0000u);
    a += v;   // <2 x float> fadd -> v_pk_add_f32
}

__global__ void zero_cursors_kernel(int* __restrict__ cur, int nb) {
    int i = blockIdx.x * blockDim.x + threadIdx.x;
    if (i < nb) cur[i] = 0;
}

// Bin edges into per-bucket regions. Packed entry: (row&511)<<17 | col.
// (Requires n <= 131072 so col fits 17 bits; n = 100000 here.)
__global__ __launch_bounds__(256) void bin_edges_kernel(const int* __restrict__ rows,
                                                        const int* __restrict__ cols,
                                                        int* __restrict__ bucket_cursor,
                                                        unsigned* __restrict__ bins,
                                                        int e, int nb) {
    __shared__ int cnt[512];
    for (int i = threadIdx.x; i < nb; i += 256) cnt[i] = 0;
    __syncthreads();
    int base = blockIdx.x * (256 * EPT) + threadIdx.x;
    int rr[EPT], cc[EPT];
#pragma unroll
    for (int k = 0; k < EPT; k++) {
        int idx = base + k * 256;
        if (idx < e) { rr[k] = rows[idx]; cc[k] = cols[idx]; }
        else { rr[k] = -1; cc[k] = 0; }
    }
#pragma unroll
    for (int k = 0; k < EPT; k++)
        if (rr[k] >= 0) atomicAdd(&cnt[rr[k] >> BROWS_LOG], 1);
    __syncthreads();
    for (int i = threadIdx.x; i < nb; i += 256) {
        int c = cnt[i];
        cnt[i] = (c > 0) ? atomicAdd(&bucket_cursor[i], c) : 0;  // global base
    }
    __syncthreads();
#pragma unroll
    for (int k = 0; k < EPT; k++) {
        if (rr[k] >= 0) {
            int b = rr[k] >> BROWS_LOG;
            int pos = atomicAdd(&cnt[b], 1);  // absolute pos within bucket
            bins[(size_t)b * BINCAP + pos] =
                ((unsigned)(rr[k] & (BROWS - 1)) << 17) | (unsigned)cc[k];
        }
    }
}

// One 512-thread block per bucket, all staged in LDS. Emits sorted,
// dummy-padded CSR (deterministic) + row_info + dis + degree-grouped perm.
__global__ __launch_bounds__(512) void build_csr_kernel(const unsigned* __restrict__ bins,
                                                        const int* __restrict__ bucket_cursor,
                                                        int* __restrict__ csr_col,
                                                        uint2* __restrict__ row_info,
                                                        float* __restrict__ dis,
                                                        int* __restrict__ perm, int n) {
    __shared__ int cnt[512];
    __shared__ int sm[512];
    __shared__ int cur[512];
    __shared__ int lcsr[CSRCAP];  // 48 KB; total static LDS = 54 KB
    int b = blockIdx.x;
    int tid = threadIdx.x;
    int m = bucket_cursor[b];
    cnt[tid] = 0;
    __syncthreads();
    const unsigned* bp = bins + (size_t)b * BINCAP;
    for (int i = tid; i < m; i += 512) atomicAdd(&cnt[bp[i] >> 17], 1);
    __syncthreads();
    int c = cnt[tid];
    int padded = (c + 3) & ~3;
    int r = b * BROWS + tid;
    if (r < n) dis[r] = rsqrtf(1.0f + (float)c);
    sm[tid] = padded;
    __syncthreads();
    for (int off = 1; off < 512; off <<= 1) {
        int t = (tid >= off) ? sm[tid - off] : 0;
        __syncthreads();
        sm[tid] += t;
        __syncthreads();
    }
    int off0 = sm[tid] - padded;  // exclusive scan
    cur[tid] = off0;
    if (r < n) row_info[r] = make_uint2((unsigned)(b * CSRCAP + off0), (unsigned)padded);
    __syncthreads();
    for (int i = tid; i < m; i += 512) {
        unsigned u = bp[i];
        int pos = atomicAdd(&cur[u >> 17], 1);
        lcsr[pos] = (int)(u & 0x1FFFFu);
    }
    __syncthreads();
    // Per-row insertion sort (determinism: sorted multiset order) + dummy pad.
    for (int i2 = off0 + 1; i2 < off0 + c; i2++) {
        int key = lcsr[i2];
        int j = i2 - 1;
        while (j >= off0 && lcsr[j] > key) { lcsr[j + 1] = lcsr[j]; j--; }
        lcsr[j + 1] = key;
    }
    for (int j = off0 + c; j < off0 + padded; j++) lcsr[j] = n;
    __syncthreads();
    int tot = sm[511];  // total padded slots (multiple of 4)
    int4* cp4 = (int4*)(csr_col + (size_t)b * CSRCAP);
    const int4* l4 = (const int4*)lcsr;
    for (int i = tid; i < (tot >> 2); i += 512) cp4[i] = l4[i];

    // ---- degree-grouped perm: counting sort of bucket rows by padded len ----
    // (rank order within a bin is nondeterministic, but output is per-row
    //  independent of wave assignment -> bit-identical results.)
    if (tid < 64) cnt[tid] = 0;
    __syncthreads();
    int bin = min(padded >> 2, 63);
    if (r < n) atomicAdd(&cnt[bin], 1);
    __syncthreads();
    if (tid < 64) sm[tid] = cnt[tid];
    __syncthreads();
    for (int off = 1; off < 64; off <<= 1) {
        int t = (tid >= off && tid < 64) ? sm[tid - off] : 0;
        __syncthreads();
        if (tid < 64) sm[tid] += t;
        __syncthreads();
    }
    if (tid < 64) cur[tid] = sm[tid] - cnt[tid];  // exclusive bin base
    __syncthreads();
    if (r < n) {
        int rank = atomicAdd(&cur[bin], 1);
        perm[b * BROWS + rank] = r;
    } else {
        perm[b * BROWS + tid] = -1;  // tid >= valid-count exactly when r >= n
    }
}

// xs0[i] = bf16(dis[i] * x[i,:]) packed 2/dword; dummy rows (n) of BOTH xs
// arrays zeroed (pad slots gather row n).
__global__ void scale_x_kernel(const float* __restrict__ x, const float* __restrict__ dis,
                               unsigned* __restrict__ xs0, unsigned* __restrict__ xs1, int n) {
    int i = blockIdx.x * blockDim.x + threadIdx.x;  // over (n+1)*32 dwords
    int total = (n + 1) * (D_FEAT / 2);
    if (i >= total) return;
    int node = i >> 5;
    if (node < n) {
        float s = dis[node];
        float2 v = ((const float2*)x)[i];
        xs0[i] = pack_bf16_2(s * v.x, s * v.y);
    } else {
        xs0[i] = 0u;
        xs1[i] = 0u;  // dummy row of hop-1 output
    }
}

// Gather 16 slots (4 predicated groups of 4) for one quarter's row chunk.
// Accumulates into v2f h01 (features 4ql,4ql+1) and h23 (4ql+2,4ql+3).
#define GATHER16(cp, xs_in, ql, base, len)                                  \
    uint2 u0 = make_uint2(0u, 0u), u1 = u0, u2 = u0, u3 = u0;               \
    uint2 u4 = u0, u5 = u0, u6 = u0, u7 = u0;                               \
    uint2 u8 = u0, u9 = u0, u10 = u0, u11 = u0;                             \
    uint2 u12 = u0, u13 = u0, u14 = u0, u15 = u0;                           \
    if (base < len) {                                                       \
        uint4 cv = cp[(base >> 2) + 0];                                     \
        u0 = xs_in[cv.x * 16 + ql]; u1 = xs_in[cv.y * 16 + ql];             \
        u2 = xs_in[cv.z * 16 + ql]; u3 = xs_in[cv.w * 16 + ql];             \
    }                                                                       \
    if (base + 4 < len) {                                                   \
        uint4 cv = cp[(base >> 2) + 1];                                     \
        u4 = xs_in[cv.x * 16 + ql]; u5 = xs_in[cv.y * 16 + ql];             \
        u6 = xs_in[cv.z * 16 + ql]; u7 = xs_in[cv.w * 16 + ql];             \
    }                                                                       \
    if (base + 8 < len) {                                                   \
        uint4 cv = cp[(base >> 2) + 2];                                     \
        u8 = xs_in[cv.x * 16 + ql]; u9 = xs_in[cv.y * 16 + ql];             \
        u10 = xs_in[cv.z * 16 + ql]; u11 = xs_in[cv.w * 16 + ql];           \
    }                                                                       \
    if (base + 12 < len) {                                                  \
        uint4 cv = cp[(base >> 2) + 3];                                     \
        u12 = xs_in[cv.x * 16 + ql]; u13 = xs_in[cv.y * 16 + ql];           \
        u14 = xs_in[cv.z * 16 + ql]; u15 = xs_in[cv.w * 16 + ql];           \
    }                                                                       \
    acc2p(u0.x, h01); acc2p(u0.y, h23);                                     \
    acc2p(u1.x, h01); acc2p(u1.y, h23);                                     \
    acc2p(u2.x, h01); acc2p(u2.y, h23);                                     \
    acc2p(u3.x, h01); acc2p(u3.y, h23);                                     \
    acc2p(u4.x, h01); acc2p(u4.y, h23);                                     \
    acc2p(u5.x, h01); acc2p(u5.y, h23);                                     \
    acc2p(u6.x, h01); acc2p(u6.y, h23);                                     \
    acc2p(u7.x, h01); acc2p(u7.y, h23);                                     \
    acc2p(u8.x, h01); acc2p(u8.y, h23);                                     \
    acc2p(u9.x, h01); acc2p(u9.y, h23);                                     \
    acc2p(u10.x, h01); acc2p(u10.y, h23);                                   \
    acc2p(u11.x, h01); acc2p(u11.y, h23);                                   \
    acc2p(u12.x, h01); acc2p(u12.y, h23);                                   \
    acc2p(u13.x, h01); acc2p(u13.y, h23);                                   \
    acc2p(u14.x, h01); acc2p(u14.y, h23);                                   \
    acc2p(u15.x, h01); acc2p(u15.y, h23);

// Hop 1: xs1[r,:] = bf16( dis[r]^2 * ( xs0[r,:] + sum_c xs0[c,:] ) ).
// Wave w processes rows perm[4w+q]; lane (q,ql) holds features 4ql..4ql+3.
__global__ __launch_bounds__(256, 6) void spmm_hop1_kernel(const uint2* __restrict__ xs_in,
                                                           uint2* __restrict__ xs_out,
                                                           const int* __restrict__ perm,
                                                           const uint2* __restrict__ row_info,
                                                           const int* __restrict__ csr_col,
                                                           const float* __restrict__ dis,
                                                           int n, int nperm) {
    int wave = (blockIdx.x * blockDim.x + threadIdx.x) >> 6;
    int lane = threadIdx.x & 63;
    int q = lane >> 4, ql = lane & 15;
    int pidx = wave * 4 + q;
    int r = (pidx < nperm) ? perm[pidx] : -1;
    bool valid = (r >= 0);
    int s = 0, len = 0;
    if (valid) { uint2 info = row_info[r]; s = (int)info.x; len = (int)info.y; }
    int maxlen = len;
    maxlen = max(maxlen, __shfl_xor(maxlen, 16, 64));
    maxlen = max(maxlen, __shfl_xor(maxlen, 32, 64));

    v2f h01 = {0.f, 0.f}, h23 = {0.f, 0.f};
    const uint4* cp = (const uint4*)(csr_col + s);  // s is a multiple of 4
    for (int base = 0; base < maxlen; base += 16) {
        GATHER16(cp, xs_in, ql, base, len)
    }
    if (valid) {
        uint2 us = xs_in[r * 16 + ql];  // self term
        acc2p(us.x, h01); acc2p(us.y, h23);
        float dr = dis[r];
        float dr2 = dr * dr;
        xs_out[r * 16 + ql] = make_uint2(pack_bf16_2(dr2 * h01.x, dr2 * h01.y),
                                         pack_bf16_2(dr2 * h23.x, dr2 * h23.y));
    }
}

// Hop 2 fused with logits + log_softmax. h2[r,:] = dis[r]*(xs1[r,:]+sum_c xs1[c,:]).
// GEMV: per-wave LDS transpose of h (hl, padded) + transposed padded Wt;
// lane ql covers classes ql, ql+16, (ql<8) ql+32. Inner loop is broadcast
// ds_read_b128 + FMA only (no shfl, no scalar W reads).
__global__ __launch_bounds__(256, 6) void spmm_logits_kernel(const uint2* __restrict__ xs_in,
                                                             const int* __restrict__ perm,
                                                             const uint2* __restrict__ row_info,
                                                             const int* __restrict__ csr_col,
                                                             const float* __restrict__ dis,
                                                             const float* __restrict__ W,
                                                             const float* __restrict__ b,
                                                             float* __restrict__ out,
                                                             int n, int nperm) {
    __shared__ float Wt[NCLS][D_FEAT + 4];  // transposed, padded: 2-lane/bank max
    __shared__ float bl[NCLS];
    __shared__ float hl[16][D_FEAT + 4];    // 4 waves x 4 rows; padded rows
    for (int i = threadIdx.x; i < D_FEAT * NCLS; i += 256) {
        int d = i / NCLS, cc = i - d * NCLS;
        Wt[cc][d] = W[i];
    }
    for (int i = threadIdx.x; i < NCLS; i += 256) bl[i] = b[i];
    __syncthreads();

    int wave = (blockIdx.x * blockDim.x + threadIdx.x) >> 6;
    int lane = threadIdx.x & 63;
    int q = lane >> 4, ql = lane & 15;
    int pidx = wave * 4 + q;
    int r = (pidx < nperm) ? perm[pidx] : -1;
    bool valid = (r >= 0);
    int s = 0, len = 0;
    if (valid) { uint2 info = row_info[r]; s = (int)info.x; len = (int)info.y; }
    int maxlen = len;
    maxlen = max(maxlen, __shfl_xor(maxlen, 16, 64));
    maxlen = max(maxlen, __shfl_xor(maxlen, 32, 64));

    v2f h01 = {0.f, 0.f}, h23 = {0.f, 0.f};
    const uint4* cp = (const uint4*)(csr_col + s);
    for (int base = 0; base < maxlen; base += 16) {
        GATHER16(cp, xs_in, ql, base, len)
    }

    float y0, y1, y2;
    int c0 = ql, c1 = ql + 16;
    int c2 = (ql < 8) ? (ql + 32) : ql;  // dup addr -> broadcast, no conflict
    {
        uint2 us = valid ? xs_in[r * 16 + ql] : make_uint2(0u, 0u);  // self term
        acc2p(us.x, h01); acc2p(us.y, h23);
        float dr = valid ? dis[r] : 0.f;
        float h0 = h01.x * dr, h1 = h01.y * dr, h2 = h23.x * dr, h3 = h23.y * dr;

        // per-wave transpose: row's 64 features laid out in hl[rowslot][*].
        // Same-wave produce->consume via LDS (lockstep; compiler inserts
        // lgkmcnt ordering for may-alias LDS ops) -- no barrier needed.
        int rowslot = ((threadIdx.x >> 6) << 2) + q;
        *(float4*)&hl[rowslot][ql * 4] = make_float4(h0, h1, h2, h3);

        y0 = bl[c0]; y1 = bl[c1]; y2 = bl[c2];
#pragma unroll
        for (int g = 0; g < 16; g++) {
            float4 hv = *(const float4*)&hl[rowslot][g * 4];   // quarter-broadcast
            float4 w0 = *(const float4*)&Wt[c0][g * 4];
            float4 w1 = *(const float4*)&Wt[c1][g * 4];
            float4 w2 = *(const float4*)&Wt[c2][g * 4];
            y0 += hv.x * w0.x + hv.y * w0.y + hv.z * w0.z + hv.w * w0.w;
            y1 += hv.x * w1.x + hv.y * w1.y + hv.z * w1.z + hv.w * w1.w;
            y2 += hv.x * w2.x + hv.y * w2.y + hv.z * w2.z + hv.w * w2.w;
        }
    }

    bool has3 = (ql < 8);
    float m = fmaxf(y0, y1);
    if (has3) m = fmaxf(m, y2);
#pragma unroll
    for (int o = 8; o > 0; o >>= 1) m = fmaxf(m, __shfl_xor(m, o, 64));
    float sm = __expf(y0 - m) + __expf(y1 - m) + (has3 ? __expf(y2 - m) : 0.f);
#pragma unroll
    for (int o = 8; o > 0; o >>= 1) sm += __shfl_xor(sm, o, 64);
    float lse = m + __logf(sm);

    if (valid) {
        float* op = out + (long long)r * NCLS;
        op[ql] = y0 - lse;
        op[ql + 16] = y1 - lse;
        if (has3) op[ql + 32] = y2 - lse;
    }
}

extern "C" void kernel_launch(void* const* d_in, const int* in_sizes, int n_in,
                              void* d_out, int out_size, void* d_ws, size_t ws_size,
                              hipStream_t stream) {
    const float* x  = (const float*)d_in[0];
    const int*   ei = (const int*)d_in[1];   // [2, E] flat: rows then cols (int32)
    const float* W  = (const float*)d_in[2]; // [64, 40]
    const float* b  = (const float*)d_in[3]; // [40]
    float* out = (float*)d_out;

    const int n = in_sizes[0] / D_FEAT;      // 100000
    const int e = in_sizes[1] / 2;           // 1600000
    const int nb = (n + BROWS - 1) / BROWS;  // 196

    const int* rows = ei;
    const int* cols = ei + e;

    // ws layout (int units, segments aligned):
    //   bucket_cursor[nb] | dis[n] | row_info[n] (uint2) | perm[nb*512] |
    //   bins[nb*BINCAP] | csr_col[nb*CSRCAP] | xs0 | xs1       (~45 MB)
    size_t na = ((size_t)n + 256) & ~(size_t)255;
    size_t npm = (size_t)nb * BROWS;         // multiple of 512
    int*      bucket_cursor = (int*)d_ws;
    float*    dis           = (float*)(bucket_cursor + 256);
    uint2*    row_info      = (uint2*)(dis + na);
    int*      perm          = (int*)(row_info + na);
    unsigned* bins          = (unsigned*)(perm + npm);
    int*      csr_col       = (int*)(bins + (size_t)nb * BINCAP);
    unsigned* xs0           = (unsigned*)(csr_col + (size_t)nb * CSRCAP);
    unsigned* xs1           = xs0 + (size_t)(n + 1) * (D_FEAT / 2);

    const int BS = 256;

    zero_cursors_kernel<<<1, 256, 0, stream>>>(bucket_cursor, nb);
    {
        int blocks = (e + BS * EPT - 1) / (BS * EPT);  // 250
        bin_edges_kernel<<<blocks, BS, 0, stream>>>(rows, cols, bucket_cursor, bins, e, nb);
    }
    build_csr_kernel<<<nb, 512, 0, stream>>>(bins, bucket_cursor, csr_col, row_info, dis,
                                             perm, n);
    {
        int tot = (n + 1) * (D_FEAT / 2);
        scale_x_kernel<<<(tot + BS - 1) / BS, BS, 0, stream>>>(x, dis, xs0, xs1, n);
    }

    int nperm = (int)npm;                    // nb*512 perm slots
    int nwaves = nperm / 4;                  // 4 rows per wave
    int blocks = (nwaves * 64 + BS - 1) / BS;
    spmm_hop1_kernel<<<blocks, BS, 0, stream>>>((const uint2*)xs0, (uint2*)xs1, perm,
                                                row_info, csr_col, dis, n, nperm);
    spmm_logits_kernel<<<blocks, BS, 0, stream>>>((const uint2*)xs1, perm, row_info, csr_col,
                                                  dis, W, b, out, n, nperm);
}